// Round 10
// baseline (99.599 us; speedup 1.0000x reference)
//
#include <hip/hip_runtime.h>
#include <hip/hip_fp16.h>

typedef unsigned int u32;
typedef unsigned short u16;
typedef __attribute__((ext_vector_type(8))) _Float16 f16x8;
typedef __attribute__((ext_vector_type(4))) float f32x4;
typedef __attribute__((ext_vector_type(4))) u32 u32x4;

#define M_DIM 256
#define K_DIM 4096
#define N_DIM 14336
#define BM 128
#define BN 128
#define BK 64
#define KHALF (K_DIM / 2)            // 2048 per k-split block
#define NITER (KHALF / BK)           // 32
#define NBLK 448                     // 2 ksplit * 2 m * 112 n
#define LDA 72                       // halfwords per LDS row (144 B)

union U4F8 { u32x4 u; f16x8 v; };

// dequant one int32 (8 nibbles, k-order [0,4,1,5,2,6,3,7]) -> f16x8 fragment
// w = RN( RN(s*q) - z ): d2 = -1024*s is EXACT in f16 -> bit-identical to ref.
__device__ __forceinline__ f16x8 dq8(u32 q, __half2 s2, __half2 d2, __half2 z2) {
  const u32 q1 = q >> 4, q2 = q >> 8, q3 = q >> 12;
  U4F8 r;
  const u32 x0 = ( q & 0x000F000Fu) | 0x64006400u;   // {1024+n_j, 1024+n_{j+4}}
  const u32 x1 = (q1 & 0x000F000Fu) | 0x64006400u;
  const u32 x2 = (q2 & 0x000F000Fu) | 0x64006400u;
  const u32 x3 = (q3 & 0x000F000Fu) | 0x64006400u;
  r.u.x = __builtin_bit_cast(u32, __hsub2(__hfma2(__builtin_bit_cast(__half2, x0), s2, d2), z2));
  r.u.y = __builtin_bit_cast(u32, __hsub2(__hfma2(__builtin_bit_cast(__half2, x1), s2, d2), z2));
  r.u.z = __builtin_bit_cast(u32, __hsub2(__hfma2(__builtin_bit_cast(__half2, x2), s2, d2), z2));
  r.u.w = __builtin_bit_cast(u32, __hsub2(__hfma2(__builtin_bit_cast(__half2, x3), s2, d2), z2));
  return r.v;
}

__device__ __forceinline__ u32 pkrtz(float a, float b) {  // exact: x was f16
  return __builtin_bit_cast(u32, __builtin_amdgcn_cvt_pkrtz(a, b));
}

__global__ void zero_out(float* __restrict__ O) {
  const size_t i = (size_t)blockIdx.x * 256 + threadIdx.x;   // 917,504 f32x4 exact
  ((f32x4*)O)[i] = (f32x4){0.f, 0.f, 0.f, 0.f};
}

__global__ __launch_bounds__(256, 2) void kivi_gemm(
    const float* __restrict__ X,    // x upconverted to f32 [256][4096]
    const int* __restrict__ QW,     // [512][14336]; nibble j of row r -> k = r*8+j
    const float* __restrict__ S,    // [32][14336]
    const float* __restrict__ Z,    // [32][14336]
    float* __restrict__ O)          // out f32 [256][14336], pre-zeroed
{
  __shared__ __align__(16) u16 As[2][BM][LDA];   // 36,864 B
  __shared__ __align__(16) u16 Bs[2][BN][LDA];   // 36,864 B (73.7 KB total)

  const int tid  = threadIdx.x;
  const int lane = tid & 63;
  const int w    = tid >> 6;

  // XCD-aware bijective swizzle: 448 = 8*56. Within an XCD: same (kh, mt),
  // 56 consecutive n-tiles -> shared 1MB A panel stays L2-resident.
  const int b   = blockIdx.x;
  const int L   = (b & 7) * 56 + (b >> 3);
  const int kh  = L / 224;
  const int rem = L % 224;
  const int mt  = rem / 112;
  const int nt  = rem % 112;
  const int m0  = mt * BM;
  const int n0  = nt * BN;
  const int kb  = kh * KHALF;          // k base (elements)
  const int kb8 = kh * (KHALF / 8);    // k base (QW rows)

  // 4 waves = 2m x 2n wave-tiles of 64x64; frags 4m x 4n x 2ks
  const int wm = w >> 1, wn = w & 1;
  const int mb = wm * 64, nb = wn * 64;
  const int fr = lane & 15, fq = lane >> 4;

  // A staging: thread -> row tid>>1 (0..127), k-segment (tid&1)*32 (32 f32)
  const int arow = tid >> 1;
  const int aseg = tid & 1;
  // B staging: thread -> col tid>>1 (0..127), k8-chunks (tid&1)*4 + 0..3
  const int bcol  = tid >> 1;
  const int bhalf = tid & 1;
  const int colg  = n0 + bcol;

  f32x4 acc[4][4];
#pragma unroll
  for (int mi = 0; mi < 4; ++mi)
#pragma unroll
    for (int ni = 0; ni < 4; ++ni)
      acc[mi][ni] = (f32x4){0.f, 0.f, 0.f, 0.f};

  f32x4 aR[8];
  u32 qR[4];
  float sv, zv;

  auto loadA = [&](int t) {
    const float* p = X + (size_t)(m0 + arow) * K_DIM + kb + t * BK + aseg * 32;
#pragma unroll
    for (int c = 0; c < 8; ++c) aR[c] = *(const f32x4*)(p + c * 4);
  };
  // sigma-pack pairs (j, j+4) per 8-chunk to match dq8 k-order; 4x b128 writes
  auto writeA = [&](int buf) {
#pragma unroll
    for (int c = 0; c < 4; ++c) {
      u32x4 pk;
      pk.x = pkrtz(aR[c * 2][0], aR[c * 2 + 1][0]);
      pk.y = pkrtz(aR[c * 2][1], aR[c * 2 + 1][1]);
      pk.z = pkrtz(aR[c * 2][2], aR[c * 2 + 1][2]);
      pk.w = pkrtz(aR[c * 2][3], aR[c * 2 + 1][3]);
      *(u32x4*)&As[buf][arow][aseg * 32 + c * 8] = pk;
    }
  };
  auto loadB = [&](int t) {
    const size_t rbase = (size_t)(kb8 + t * 8 + bhalf * 4) * N_DIM + colg;
#pragma unroll
    for (int j = 0; j < 4; ++j)
      qR[j] = *(const u32*)(QW + rbase + (size_t)j * N_DIM);
    const int g = kh * 16 + (t >> 1);          // GROUP_SIZE=128 = 2 K-steps
    sv = S[(size_t)g * N_DIM + colg];
    zv = Z[(size_t)g * N_DIM + colg];
  };
  auto writeB = [&](int buf) {
    const __half sh = __float2half(sv);                 // matches ref astype(f16)
    const __half zh = __float2half(zv);
    const __half dh = __hmul(sh, __float2half(-1024.f)); // exact: exponent shift
    const __half2 s2 = __halves2half2(sh, sh);
    const __half2 d2 = __halves2half2(dh, dh);
    const __half2 z2 = __halves2half2(zh, zh);
#pragma unroll
    for (int j = 0; j < 4; ++j) {
      const f16x8 v = dq8(qR[j], s2, d2, z2);
      *(f16x8*)&Bs[buf][bcol][(bhalf * 4 + j) * 8] = v;
    }
  };

  // prologue
  loadA(0); loadB(0);
  writeA(0); writeB(0);
  __syncthreads();

#pragma unroll 1
  for (int t = 0; t < NITER; ++t) {
    const int cur = t & 1;
    const bool pf = (t + 1 < NITER);
    if (pf) { loadA(t + 1); loadB(t + 1); }   // globals issued at iter top

#pragma unroll
    for (int ks = 0; ks < 2; ++ks) {
      f16x8 af[4], bf[4];
#pragma unroll
      for (int mi = 0; mi < 4; ++mi)
        af[mi] = *(const f16x8*)&As[cur][mb + mi * 16 + fr][ks * 32 + fq * 8];
#pragma unroll
      for (int ni = 0; ni < 4; ++ni)
        bf[ni] = *(const f16x8*)&Bs[cur][nb + ni * 16 + fr][ks * 32 + fq * 8];
#pragma unroll
      for (int mi = 0; mi < 4; ++mi)
#pragma unroll
        for (int ni = 0; ni < 4; ++ni)
          acc[mi][ni] = __builtin_amdgcn_mfma_f32_16x16x32_f16(
              af[mi], bf[ni], acc[mi][ni], 0, 0, 0);
    }

    if (pf) { writeA(cur ^ 1); writeB(cur ^ 1); }  // fill other buffer
    __syncthreads();
  }

  // epilogue: k-split partial -> atomicAdd (exactly 2 commutative addends/output)
#pragma unroll
  for (int mi = 0; mi < 4; ++mi)
#pragma unroll
    for (int ni = 0; ni < 4; ++ni)
#pragma unroll
      for (int r = 0; r < 4; ++r) {
        const int row = m0 + mb + mi * 16 + fq * 4 + r;
        const int col = n0 + nb + ni * 16 + fr;
        atomicAdd(&O[(size_t)row * N_DIM + col], acc[mi][ni][r]);
      }
}

extern "C" void kernel_launch(void* const* d_in, const int* in_sizes, int n_in,
                              void* d_out, int out_size, void* d_ws, size_t ws_size,
                              hipStream_t stream) {
  const float* X  = (const float*)d_in[0];
  const int*   QW = (const int*)d_in[1];
  const float* S  = (const float*)d_in[2];
  const float* Zp = (const float*)d_in[3];
  float* O = (float*)d_out;
  hipLaunchKernelGGL(zero_out, dim3(3584), dim3(256), 0, stream, O);
  hipLaunchKernelGGL(kivi_gemm, dim3(NBLK), dim3(256), 0, stream, X, QW, S, Zp, O);
}

// Round 11
// 65.759 us; speedup vs baseline: 1.5146x; 1.5146x over previous
//
#include <hip/hip_runtime.h>
#include <hip/hip_fp16.h>

typedef unsigned int u32;
typedef unsigned short u16;
typedef __attribute__((ext_vector_type(8))) _Float16 f16x8;
typedef __attribute__((ext_vector_type(4))) float f32x4;
typedef __attribute__((ext_vector_type(4))) u32 u32x4;

#define M_DIM 256
#define K_DIM 4096
#define N_DIM 14336
#define BM 64
#define BN 128
#define BK 64
#define KHALF (K_DIM / 2)       // 2048 per k-split block
#define NITER (KHALF / BK)      // 32 (divisible by 4 for the unroll)
#define NBLK 896                // 2 kh * 4 mt * 112 nt
#define LDA 72                  // u16 per LDS row (144 B)

union U4F8 { u32x4 u; f16x8 v; };

// dequant one int32 (8 nibbles, k-order [0,4,1,5,2,6,3,7]) -> f16x8 fragment
// w = RN( RN(s*q) - z ): d2 = -1024*s is EXACT in f16 -> bit-identical to ref.
__device__ __forceinline__ f16x8 dq8(u32 q, __half2 s2, __half2 d2, __half2 z2) {
  const u32 q1 = q >> 4, q2 = q >> 8, q3 = q >> 12;
  U4F8 r;
  const u32 x0 = ( q & 0x000F000Fu) | 0x64006400u;   // {1024+n_j, 1024+n_{j+4}}
  const u32 x1 = (q1 & 0x000F000Fu) | 0x64006400u;
  const u32 x2 = (q2 & 0x000F000Fu) | 0x64006400u;
  const u32 x3 = (q3 & 0x000F000Fu) | 0x64006400u;
  r.u.x = __builtin_bit_cast(u32, __hsub2(__hfma2(__builtin_bit_cast(__half2, x0), s2, d2), z2));
  r.u.y = __builtin_bit_cast(u32, __hsub2(__hfma2(__builtin_bit_cast(__half2, x1), s2, d2), z2));
  r.u.z = __builtin_bit_cast(u32, __hsub2(__hfma2(__builtin_bit_cast(__half2, x2), s2, d2), z2));
  r.u.w = __builtin_bit_cast(u32, __hsub2(__hfma2(__builtin_bit_cast(__half2, x3), s2, d2), z2));
  return r.v;
}

__device__ __forceinline__ u32 pkrtz(float a, float b) {  // exact: x was f16
  return __builtin_bit_cast(u32, __builtin_amdgcn_cvt_pkrtz(a, b));
}

__global__ void zero_out(float* __restrict__ O) {
  const size_t i = (size_t)blockIdx.x * 256 + threadIdx.x;   // 917,504 f32x4 exact
  ((f32x4*)O)[i] = (f32x4){0.f, 0.f, 0.f, 0.f};
}

__global__ __launch_bounds__(256, 3) void kivi_gemm(
    const float* __restrict__ X,    // x upconverted to f32 [256][4096]
    const int* __restrict__ QW,     // [512][14336]; nibble j of row r -> k = r*8+j
    const float* __restrict__ S,    // [32][14336]
    const float* __restrict__ Z,    // [32][14336]
    float* __restrict__ O)          // out f32 [256][14336], pre-zeroed
{
  __shared__ __align__(16) u16 As[2][BM][LDA];   // 18,432 B (A only; B in regs)

  const int tid  = threadIdx.x;
  const int lane = tid & 63;
  const int wn   = tid >> 6;        // 4 waves = 4 n-subtiles of 32 cols

  // XCD swizzle: 896 = 8*112. Within an XCD chunk: mt minor -> 4 mt blocks
  // share each QW panel (L2), 28 consecutive nt share the X panel.
  const int b   = blockIdx.x;
  const int L   = (b & 7) * 112 + (b >> 3);
  const int kh  = L / 448;              // 0..1 k-split half
  const int rem = L % 448;
  const int nt  = rem >> 2;             // 0..111
  const int mt  = rem & 3;              // 0..3
  const int m0  = mt * BM;
  const int n0  = nt * BN;
  const int kb  = kh * KHALF;           // k base (elements)
  const int kb8 = kh * (KHALF / 8);     // k base (QW rows)

  // wave-tile 64x32: frags 4m x 2n x 2ks (16 MFMA/iter); dup = 256/64 = 4x
  const int fr = lane & 15, fq = lane >> 4;
  const int cb = n0 + wn * 32 + fr;     // B col for ni=0 (ni=1 -> +16)

  // A staging: thread -> row tid>>2 (0..63), 16 f32 at seg (tid&3)*16
  const int arow = tid >> 2;
  const int aseg = (tid & 3) * 16;

  f32x4 acc[4][2];
#pragma unroll
  for (int mi = 0; mi < 4; ++mi)
#pragma unroll
    for (int ni = 0; ni < 2; ++ni)
      acc[mi][ni] = (f32x4){0.f, 0.f, 0.f, 0.f};

  f32x4 aR[4];                       // A depth-1 staging regs
  u32 q0[2][2], q1[2][2], q2[2][2], q3[2][2];     // B depth-2: 4 static sets
  float s0[2], z0[2], s1[2], z1[2], s2[2], z2[2], s3[2], z3[2];

  auto loadAx = [&](int t) {
    const float* p = X + (size_t)(m0 + arow) * K_DIM + kb + t * BK + aseg;
    aR[0] = *(const f32x4*)(p);
    aR[1] = *(const f32x4*)(p + 4);
    aR[2] = *(const f32x4*)(p + 8);
    aR[3] = *(const f32x4*)(p + 12);
  };
  // sigma-pack pairs (j, j+4) to match dq8 k-order; two b128 writes
  auto writeAx = [&](int buf) {
#pragma unroll
    for (int c = 0; c < 2; ++c) {
      u32x4 pk;
      pk.x = pkrtz(aR[c * 2][0], aR[c * 2 + 1][0]);
      pk.y = pkrtz(aR[c * 2][1], aR[c * 2 + 1][1]);
      pk.z = pkrtz(aR[c * 2][2], aR[c * 2 + 1][2]);
      pk.w = pkrtz(aR[c * 2][3], aR[c * 2 + 1][3]);
      *(u32x4*)&As[buf][arow][aseg + c * 8] = pk;
    }
  };
  auto loadBq = [&](int t, u32 (&q)[2][2], float (&s)[2], float (&z)[2]) {
    const size_t rbase = (size_t)(kb8 + t * 8 + fq) * N_DIM + cb;
#pragma unroll
    for (int ks = 0; ks < 2; ++ks)
#pragma unroll
      for (int ni = 0; ni < 2; ++ni)
        q[ks][ni] = *(const u32*)(QW + rbase + (size_t)ks * 4 * N_DIM + ni * 16);
    const int g = kh * 16 + (t >> 1);          // GROUP_SIZE=128 = 2 K-steps
#pragma unroll
    for (int ni = 0; ni < 2; ++ni) {
      s[ni] = S[(size_t)g * N_DIM + cb + ni * 16];
      z[ni] = Z[(size_t)g * N_DIM + cb + ni * 16];
    }
  };
  auto computeT = [&](int buf, const u32 (&q)[2][2],
                      const float (&s)[2], const float (&z)[2]) {
    const __half hneg1024 = __float2half(-1024.f);
    __half2 sh2[2], dh2[2], zh2[2];
#pragma unroll
    for (int ni = 0; ni < 2; ++ni) {
      const __half sh = __float2half(s[ni]);   // matches ref astype(f16)
      const __half zh = __float2half(z[ni]);
      const __half dh = __hmul(sh, hneg1024);  // exact: exponent shift
      sh2[ni] = __halves2half2(sh, sh);
      dh2[ni] = __halves2half2(dh, dh);
      zh2[ni] = __halves2half2(zh, zh);
    }
#pragma unroll
    for (int ks = 0; ks < 2; ++ks) {
      f16x8 af[4], bf[2];
#pragma unroll
      for (int mi = 0; mi < 4; ++mi)
        af[mi] = *(const f16x8*)&As[buf][mi * 16 + fr][ks * 32 + fq * 8];
#pragma unroll
      for (int ni = 0; ni < 2; ++ni)
        bf[ni] = dq8(q[ks][ni], sh2[ni], dh2[ni], zh2[ni]);
#pragma unroll
      for (int mi = 0; mi < 4; ++mi)
#pragma unroll
        for (int ni = 0; ni < 2; ++ni)
          acc[mi][ni] = __builtin_amdgcn_mfma_f32_16x16x32_f16(
              af[mi], bf[ni], acc[mi][ni], 0, 0, 0);
    }
  };

#define LGKM_BARRIER() do {                                    \
    asm volatile("s_waitcnt lgkmcnt(0)" ::: "memory");         \
    __builtin_amdgcn_s_barrier();                              \
  } while (0)

  // prologue: A(0) -> buf0; B sets for t=0,1 in flight
  loadAx(0);
  loadBq(0, q0, s0, z0);
  loadBq(1, q1, s1, z1);
  writeAx(0);
  LGKM_BARRIER();

#pragma unroll 1
  for (int tb = 0; tb < NITER; tb += 4) {
    // phase 0: t=tb (buf0, set0); prefetch A(t+1), B(t+2)->set2
    loadAx(tb + 1);
    loadBq(tb + 2, q2, s2, z2);
    __builtin_amdgcn_sched_barrier(0);
    computeT(0, q0, s0, z0);
    writeAx(1);
    LGKM_BARRIER();

    // phase 1: t=tb+1 (buf1, set1); prefetch A(t+2), B(t+3)->set3
    loadAx(tb + 2);
    loadBq(tb + 3, q3, s3, z3);
    __builtin_amdgcn_sched_barrier(0);
    computeT(1, q1, s1, z1);
    writeAx(0);
    LGKM_BARRIER();

    // phase 2: t=tb+2 (buf0, set2); prefetch A(t+3), B(t+4)->set0
    loadAx(tb + 3);
    if (tb + 4 < NITER) loadBq(tb + 4, q0, s0, z0);
    __builtin_amdgcn_sched_barrier(0);
    computeT(0, q2, s2, z2);
    writeAx(1);
    LGKM_BARRIER();

    // phase 3: t=tb+3 (buf1, set3); prefetch A(t+4), B(t+5)->set1
    if (tb + 4 < NITER) loadAx(tb + 4);
    if (tb + 5 < NITER) loadBq(tb + 5, q1, s1, z1);
    __builtin_amdgcn_sched_barrier(0);
    computeT(1, q3, s3, z3);
    if (tb + 4 < NITER) writeAx(0);
    LGKM_BARRIER();
  }
#undef LGKM_BARRIER

  // epilogue: k-split partial -> atomicAdd (exactly 2 commutative addends/output)
#pragma unroll
  for (int mi = 0; mi < 4; ++mi)
#pragma unroll
    for (int ni = 0; ni < 2; ++ni)
#pragma unroll
      for (int r = 0; r < 4; ++r) {
        const int row = m0 + mi * 16 + fq * 4 + r;
        const int col = n0 + wn * 32 + ni * 16 + fr;
        atomicAdd(&O[(size_t)row * N_DIM + col], acc[mi][ni][r]);
      }
}

extern "C" void kernel_launch(void* const* d_in, const int* in_sizes, int n_in,
                              void* d_out, int out_size, void* d_ws, size_t ws_size,
                              hipStream_t stream) {
  const float* X  = (const float*)d_in[0];
  const int*   QW = (const int*)d_in[1];
  const float* S  = (const float*)d_in[2];
  const float* Zp = (const float*)d_in[3];
  float* O = (float*)d_out;
  hipLaunchKernelGGL(zero_out, dim3(3584), dim3(256), 0, stream, O);
  hipLaunchKernelGGL(kivi_gemm, dim3(NBLK), dim3(256), 0, stream, X, QW, S, Zp, O);
}